// Round 1
// baseline (76.259 us; speedup 1.0000x reference)
//
#include <hip/hip_runtime.h>

// Problem constants: x[B,N], WQ/WK/WV[H,N], W0[H]; out[B,N] fp32.
#define N      4096
#define BATCH  4
#define NHEAD  4
#define DEG    12              // Taylor degree; |s*k| ~ 0.2 -> trunc err ~1e-18 rel
#define NSLOT  25              // M_1..M_12 (12 slots) + P_0..P_12 (13 slots)
#define BLK    256
#define NTILE  (N / BLK)       // 16 output tiles per batch row
#define LOG2E  1.4426950408889634f

// Rank-1 softmax attention via moment expansion:
//   out_h[b,i] = (Nm(s_i) - e^{s_i k_i} v_i) / D(s_i),  s_i = x[b,i]*wq[i]
//   D(s)  = sum_j e^{s k_j}     = sum_m s^m/m! * M_m,  M_m = sum_j k_j^m
//   Nm(s) = sum_j e^{s k_j} v_j = sum_m s^m/m! * P_m,  P_m = sum_j k_j^m v_j
// (diagonal masked AFTER softmax -> denominator keeps it; numerator drops it)
//
// FUSED single-kernel design: each block (b, itile) redundantly recomputes the
// 4 heads' moments over the full N (compute is ~2.5K VALU inst/thread — a
// rounding error vs. launch overhead), holds the 4x(13+13) Horner coefficients
// in LDS, then evaluates its own 256-output tile. No workspace, no second
// launch, no grid sync, no atomics.
__global__ __launch_bounds__(BLK) void fused_attn(
    const float* __restrict__ x, const float* __restrict__ WQ,
    const float* __restrict__ WK, const float* __restrict__ WV,
    const float* __restrict__ W0, float* __restrict__ out)
{
    const int itile = blockIdx.x % NTILE;
    const int b     = blockIdx.x / NTILE;
    const float* xb = x + b * N;

    __shared__ float red[4][NSLOT];        // per-wave partials (reused per head)
    __shared__ float cD[NHEAD][DEG + 1];   // D-poly coefficients (M_m/m!)
    __shared__ float cP[NHEAD][DEG + 1];   // N-poly coefficients (P_m/m!)

    const int wid  = threadIdx.x >> 6;
    const int lane = threadIdx.x & 63;

    // Preload this thread's 16 x-values (4 coalesced float4 groups, strided
    // N/4 apart) — reused across all 4 heads.
    float4 xv[4];
    #pragma unroll
    for (int g = 0; g < 4; ++g)
        xv[g] = *(const float4*)(xb + g * (N / 4) + threadIdx.x * 4);

    constexpr float invf[DEG + 1] = {
        1.0f, 1.0f, 0.5f, 1.0f/6.0f, 1.0f/24.0f, 1.0f/120.0f, 1.0f/720.0f,
        1.0f/5040.0f, 1.0f/40320.0f, 1.0f/362880.0f, 1.0f/3628800.0f,
        1.0f/39916800.0f, 1.0f/479001600.0f};

    for (int h = 0; h < NHEAD; ++h) {
        const float* wk = WK + h * N;
        const float* wv = WV + h * N;

        float acc[NSLOT];
        #pragma unroll
        for (int s = 0; s < NSLOT; ++s) acc[s] = 0.f;

        #pragma unroll
        for (int g = 0; g < 4; ++g) {
            const int j4 = g * (N / 4) + threadIdx.x * 4;
            const float4 kw = *(const float4*)(wk + j4);
            const float4 vw = *(const float4*)(wv + j4);
            const float kk[4] = {xv[g].x * kw.x, xv[g].y * kw.y,
                                 xv[g].z * kw.z, xv[g].w * kw.w};
            const float vvv[4] = {xv[g].x * vw.x, xv[g].y * vw.y,
                                  xv[g].z * vw.z, xv[g].w * vw.w};
            #pragma unroll
            for (int e = 0; e < 4; ++e) {
                const float k = kk[e], v = vvv[e];
                acc[12] += v;                          // P_0
                float t = k;                           // k^m running power
                #pragma unroll
                for (int m = 1; m <= DEG; ++m) {
                    acc[m - 1] += t;                   // M_m
                    acc[12 + m] = fmaf(t, v, acc[12 + m]);  // P_m
                    t *= k;
                }
            }
        }

        // wave butterfly reduce (64 lanes) — every lane ends with the wave sum
        #pragma unroll
        for (int off = 32; off > 0; off >>= 1) {
            #pragma unroll
            for (int s = 0; s < NSLOT; ++s) acc[s] += __shfl_xor(acc[s], off);
        }
        if (lane < NSLOT) red[wid][lane] = acc[lane];  // parallel across 25 lanes
        __syncthreads();
        if (threadIdx.x < NSLOT) {                     // cross-wave combine + scale
            const int s = threadIdx.x;
            const float val = red[0][s] + red[1][s] + red[2][s] + red[3][s];
            if (s < DEG) cD[h][s + 1] = val * invf[s + 1];
            else         cP[h][s - DEG] = val * invf[s - DEG];
        } else if (threadIdx.x == NSLOT) {
            cD[h][0] = (float)N;                       // M_0 = N exactly
        }
        __syncthreads();                               // red reused next head;
    }                                                  // also publishes cD/cP

    // ---- phase 2: evaluate this block's output tile ----
    const int   i  = itile * BLK + threadIdx.x;
    const float xi = xb[i];
    float r = 0.f;
    #pragma unroll
    for (int h = 0; h < NHEAD; ++h) {
        const float s  = xi * WQ[h * N + i];
        const float ki = xi * WK[h * N + i];
        const float vi = xi * WV[h * N + i];
        float D = cD[h][DEG], P = cP[h][DEG];
        #pragma unroll
        for (int m = DEG - 1; m >= 0; --m) {
            D = fmaf(D, s, cD[h][m]);
            P = fmaf(P, s, cP[h][m]);
        }
        const float ei = __builtin_amdgcn_exp2f(s * ki * LOG2E);  // diagonal term
        r = fmaf(W0[h], (P - ei * vi) / D, r);
    }
    out[b * N + i] = r;                   // single writer: no atomics, no memset
}

extern "C" void kernel_launch(void* const* d_in, const int* in_sizes, int n_in,
                              void* d_out, int out_size, void* d_ws, size_t ws_size,
                              hipStream_t stream) {
    const float* x  = (const float*)d_in[0];
    const float* WQ = (const float*)d_in[1];
    const float* WK = (const float*)d_in[2];
    const float* WV = (const float*)d_in[3];
    const float* W0 = (const float*)d_in[4];
    float* out = (float*)d_out;
    (void)d_ws; (void)ws_size;           // workspace no longer needed

    fused_attn<<<dim3(BATCH * NTILE), BLK, 0, stream>>>(x, WQ, WK, WV, W0, out);
}

// Round 2
// 65.432 us; speedup vs baseline: 1.1655x; 1.1655x over previous
//
#include <hip/hip_runtime.h>

// Problem constants: x[B,N], WQ/WK/WV[H,N], W0[H]; out[B,N] fp32.
#define N      4096
#define BATCH  4
#define NHEAD  4
#define DEG    12              // Taylor degree; |s*k| ~ 0.2 -> trunc err ~1e-18 rel
#define NSLOT  25              // M_1..M_12 (12 slots) + P_0..P_12 (13 slots)
#define NCHUNK 4               // j-chunks per (b,h) in kernel A
#define CHUNKJ (N / NCHUNK)    // 1024
#define ABLOCK 256
#define BBLOCK 256
#define LOG2E  1.4426950408889634f

// Rank-1 softmax attention via moment expansion:
//   out_h[b,i] = (Nm(s_i) - e^{s_i k_i} v_i) / D(s_i),  s_i = x[b,i]*wq[i]
//   D(s)  = sum_j e^{s k_j}     = sum_m s^m/m! * M_m,  M_m = sum_j k_j^m
//   Nm(s) = sum_j e^{s k_j} v_j = sum_m s^m/m! * P_m,  P_m = sum_j k_j^m v_j
// (diagonal masked AFTER softmax -> denominator keeps it; numerator drops it)
//
// Two-kernel structure (verified 65.3 us): momentsA computes chunk-partial
// moments with NO redundancy (64 blocks, 4 elems/thread); evalB combines and
// evaluates. A fused single-kernel variant (R1) regressed +11 us: 16x
// redundant per-thread moment work at 1 wave/SIMD occupancy costs more than
// the launch it saves.

// ws layout: ws[(bh*NCHUNK + chunk)*32 + slot]; slot 0..11 = M_1..M_12,
// slot 12..24 = P_0..P_12.
__global__ __launch_bounds__(ABLOCK) void momentsA(
    const float* __restrict__ x, const float* __restrict__ WK,
    const float* __restrict__ WV, float* __restrict__ ws)
{
    const int chunk = blockIdx.x % NCHUNK;
    const int bh    = blockIdx.x / NCHUNK;
    const int h     = bh % NHEAD;
    const int b     = bh / NHEAD;
    const float* xb = x  + b * N + chunk * CHUNKJ;
    const float* wk = WK + h * N + chunk * CHUNKJ;
    const float* wv = WV + h * N + chunk * CHUNKJ;

    float acc[NSLOT];
    #pragma unroll
    for (int s = 0; s < NSLOT; ++s) acc[s] = 0.f;

    const int j4 = threadIdx.x * 4;      // 256 threads * 4 = 1024 = CHUNKJ
    float4 xv = *(const float4*)(xb + j4);
    float4 kw = *(const float4*)(wk + j4);
    float4 vw = *(const float4*)(wv + j4);
    float kk[4] = {xv.x * kw.x, xv.y * kw.y, xv.z * kw.z, xv.w * kw.w};
    float vv[4] = {xv.x * vw.x, xv.y * vw.y, xv.z * vw.z, xv.w * vw.w};
    #pragma unroll
    for (int e = 0; e < 4; ++e) {
        const float k = kk[e], v = vv[e];
        acc[12] += v;                          // P_0
        float t = k;                           // k^m running power
        #pragma unroll
        for (int m = 1; m <= DEG; ++m) {
            acc[m - 1] += t;                   // M_m
            acc[12 + m] = fmaf(t, v, acc[12 + m]);  // P_m
            t *= k;
        }
    }
    // wave butterfly reduce (64 lanes)
    #pragma unroll
    for (int off = 32; off > 0; off >>= 1) {
        #pragma unroll
        for (int s = 0; s < NSLOT; ++s) acc[s] += __shfl_xor(acc[s], off);
    }
    __shared__ float red[4][NSLOT];
    const int wid = threadIdx.x >> 6;
    if ((threadIdx.x & 63) == 0) {
        #pragma unroll
        for (int s = 0; s < NSLOT; ++s) red[wid][s] = acc[s];
    }
    __syncthreads();
    if (threadIdx.x < NSLOT) {
        ws[(size_t)blockIdx.x * 32 + threadIdx.x] =
            red[0][threadIdx.x] + red[1][threadIdx.x] +
            red[2][threadIdx.x] + red[3][threadIdx.x];
    }
}

__global__ __launch_bounds__(BBLOCK) void evalB(
    const float* __restrict__ x, const float* __restrict__ WQ,
    const float* __restrict__ WK, const float* __restrict__ WV,
    const float* __restrict__ W0, const float* __restrict__ ws,
    float* __restrict__ out)
{
    const int ntiles = N / BBLOCK;       // 16
    const int itile  = blockIdx.x % ntiles;
    const int b      = blockIdx.x / ntiles;

    __shared__ float cD[NHEAD][DEG + 1];   // D-poly coefficients (M_m/m!)
    __shared__ float cP[NHEAD][DEG + 1];   // N-poly coefficients (P_m/m!)

    if (threadIdx.x < NHEAD * NSLOT) {     // threads 0..99: combine + scale
        const int h = threadIdx.x / NSLOT;
        const int s = threadIdx.x % NSLOT;
        const float* wsb = ws + (size_t)((b * NHEAD + h) * NCHUNK) * 32 + s;
        const float val = wsb[0] + wsb[32] + wsb[64] + wsb[96];
        constexpr float invf[DEG + 1] = {
            1.0f, 1.0f, 0.5f, 1.0f/6.0f, 1.0f/24.0f, 1.0f/120.0f, 1.0f/720.0f,
            1.0f/5040.0f, 1.0f/40320.0f, 1.0f/362880.0f, 1.0f/3628800.0f,
            1.0f/39916800.0f, 1.0f/479001600.0f};
        if (s < DEG) cD[h][s + 1] = val * invf[s + 1];
        else         cP[h][s - DEG] = val * invf[s - DEG];
    } else if (threadIdx.x < NHEAD * NSLOT + NHEAD) {
        cD[threadIdx.x - NHEAD * NSLOT][0] = (float)N;   // M_0 = N exactly
    }
    __syncthreads();

    const int   i  = itile * BBLOCK + threadIdx.x;
    const float xi = x[b * N + i];
    float r = 0.f;
    #pragma unroll
    for (int h = 0; h < NHEAD; ++h) {
        const float s  = xi * WQ[h * N + i];
        const float ki = xi * WK[h * N + i];
        const float vi = xi * WV[h * N + i];
        float D = cD[h][DEG], P = cP[h][DEG];
        #pragma unroll
        for (int m = DEG - 1; m >= 0; --m) {
            D = fmaf(D, s, cD[h][m]);
            P = fmaf(P, s, cP[h][m]);
        }
        const float ei = __builtin_amdgcn_exp2f(s * ki * LOG2E);  // diagonal term
        r = fmaf(W0[h], (P - ei * vi) / D, r);
    }
    out[b * N + i] = r;                   // single writer: no atomics, no memset
}

extern "C" void kernel_launch(void* const* d_in, const int* in_sizes, int n_in,
                              void* d_out, int out_size, void* d_ws, size_t ws_size,
                              hipStream_t stream) {
    const float* x  = (const float*)d_in[0];
    const float* WQ = (const float*)d_in[1];
    const float* WK = (const float*)d_in[2];
    const float* WV = (const float*)d_in[3];
    const float* W0 = (const float*)d_in[4];
    float* out = (float*)d_out;
    float* ws  = (float*)d_ws;           // uses 64*32*4 = 8 KB

    momentsA<<<dim3(BATCH * NHEAD * NCHUNK), ABLOCK, 0, stream>>>(x, WK, WV, ws);
    evalB<<<dim3(BATCH * (N / BBLOCK)), BBLOCK, 0, stream>>>(x, WQ, WK, WV, W0, ws, out);
}